// Round 4
// baseline (92.576 us; speedup 1.0000x reference)
//
#include <hip/hip_runtime.h>

// NLM smoothing: x[B=8, H=256, W=256, C=8] fp32, K=5, sigma=1, h=1, reflect pad.
//
// v5: RPT=2 vertical blocking in a 256-thread block (TSJ=32 x TSI=16).
// Post-mortem v3 (RPT=4, 8 waves/CU): occupancy too low, lost latency hiding.
// Post-mortem v4 (RPT=2, 512-thr block, launch_bounds(512,4)): 128-VGPR cap on
// an 8-wave block with a fully-unrolled 50-exp body -> suspected scratch
// spills (+17us). v5 keeps the RPT=2 LDS-traffic win (6 rows x 5 cols = 30 px
// reads serve 2 outputs: 894 LDS cyc/wave vs v2's 2x745) in a 4-wave block:
// grid 1024 blocks = 4 blocks/CU = 16 waves/CU; LDS 25.9 KB/block (6 fit).
// Kept: SoA float4 LDS planes (16B lane stride, conflict-free);
//       w ∝ 2^(log2e*(2c·p - |p|^2 - 0.5(dr^2+dc^2))), exp(-|c|^2) cancels in
//       the w/sum(w) normalization; |p|^2*log2e staged per pixel; raw exp2.

#define BATCH 8
#define NX 256
#define NY 256
#define HALO 2
#define TSJ 32
#define TSI 16
#define RPT 2                 // output rows per thread
#define NTHREADS 256
#define LW (TSJ + 2 * HALO)   // 36
#define LH (TSI + 2 * HALO)   // 20
#define NPIX (LW * LH)        // 720

#define LOG2E 1.4426950408889634f

__device__ __forceinline__ int reflect_idx(int v) {
    // valid for v in [-2, 257] with N=256
    if (v < 0) v = -v;
    if (v > NY - 1) v = 2 * (NY - 1) - v;
    return v;
}

__global__ __launch_bounds__(NTHREADS, 4) void nlm_kernel(const float4* __restrict__ xv,
                                                          float4* __restrict__ ov) {
    __shared__ float4 t0[NPIX];   // channels 0-3
    __shared__ float4 t1[NPIX];   // channels 4-7
    __shared__ float  tn[NPIX];   // |p|^2 * log2(e) per pixel

    const int t = threadIdx.x;
    const int bj0 = blockIdx.x * TSJ;
    const int bi0 = blockIdx.y * TSI;
    const int b = blockIdx.z;
    const int bbase = b * (NX * NY);

    // ---- stage 36x20 tile (with reflect halo) into LDS, SoA planes + norms ----
#pragma unroll
    for (int s0 = 0; s0 < NPIX; s0 += NTHREADS) {
        const int p = s0 + t;
        if (p < NPIX) {
            const int lr = p / LW;
            const int lc = p - lr * LW;
            const int gi = reflect_idx(bi0 + lr - HALO);
            const int gj = reflect_idx(bj0 + lc - HALO);
            const int gidx = (bbase + gi * NY + gj) * 2;
            const float4 v0 = xv[gidx + 0];
            const float4 v1 = xv[gidx + 1];
            t0[p] = v0;
            t1[p] = v1;
            tn[p] = (v0.x * v0.x + v0.y * v0.y + v0.z * v0.z + v0.w * v0.w +
                     v1.x * v1.x + v1.y * v1.y + v1.z * v1.z + v1.w * v1.w) * LOG2E;
        }
    }
    __syncthreads();

    // ---- per-thread: RPT=2 vertically adjacent pixels ----
    const int tj = t & (TSJ - 1);        // 0..31, contiguous within wave half
    const int ti = (t >> 5) * RPT;       // 0,2,...,14

    float4 cs0[RPT], cs1[RPT];           // centers pre-scaled by 2*log2(e)
#pragma unroll
    for (int k = 0; k < RPT; ++k) {
        const int cpix = (ti + HALO + k) * LW + (tj + HALO);
        const float4 c0 = t0[cpix];
        const float4 c1 = t1[cpix];
        const float s = 2.f * LOG2E;
        cs0[k] = make_float4(s * c0.x, s * c0.y, s * c0.z, s * c0.w);
        cs1[k] = make_float4(s * c1.x, s * c1.y, s * c1.z, s * c1.w);
    }

    float4 acc0[RPT], acc1[RPT];
    float wsum[RPT];
#pragma unroll
    for (int k = 0; k < RPT; ++k) {
        acc0[k] = make_float4(0.f, 0.f, 0.f, 0.f);
        acc1[k] = make_float4(0.f, 0.f, 0.f, 0.f);
        wsum[k] = 0.f;
    }

#pragma unroll
    for (int r = 0; r < RPT + 2 * HALO; ++r) {        // 6 neighbor rows
#pragma unroll
        for (int dc = -HALO; dc <= HALO; ++dc) {      // 5 neighbor cols
            const int pix = (ti + r) * LW + (tj + HALO + dc);
            const float4 p0 = t0[pix];
            const float4 p1 = t1[pix];
            const float pn = tn[pix];
#pragma unroll
            for (int k = 0; k < RPT; ++k) {           // feed valid centers
                const int dr = r - HALO - k;
                if (dr >= -HALO && dr <= HALO) {      // compile-time
                    // a = log2e * (2c.p - |p|^2 - 0.5*(dr^2+dc^2)); w = 2^a
                    float a = (-0.5f * LOG2E * (float)(dr * dr + dc * dc)) - pn;
                    a = fmaf(cs0[k].x, p0.x, a);
                    a = fmaf(cs0[k].y, p0.y, a);
                    a = fmaf(cs0[k].z, p0.z, a);
                    a = fmaf(cs0[k].w, p0.w, a);
                    a = fmaf(cs1[k].x, p1.x, a);
                    a = fmaf(cs1[k].y, p1.y, a);
                    a = fmaf(cs1[k].z, p1.z, a);
                    a = fmaf(cs1[k].w, p1.w, a);

                    const float w = __builtin_amdgcn_exp2f(a);

                    acc0[k].x = fmaf(w, p0.x, acc0[k].x);
                    acc0[k].y = fmaf(w, p0.y, acc0[k].y);
                    acc0[k].z = fmaf(w, p0.z, acc0[k].z);
                    acc0[k].w = fmaf(w, p0.w, acc0[k].w);
                    acc1[k].x = fmaf(w, p1.x, acc1[k].x);
                    acc1[k].y = fmaf(w, p1.y, acc1[k].y);
                    acc1[k].z = fmaf(w, p1.z, acc1[k].z);
                    acc1[k].w = fmaf(w, p1.w, acc1[k].w);
                    wsum[k] += w;
                }
            }
        }
    }

#pragma unroll
    for (int k = 0; k < RPT; ++k) {
        const float inv = 1.0f / wsum[k];
        float4 o0, o1;
        o0.x = acc0[k].x * inv; o0.y = acc0[k].y * inv;
        o0.z = acc0[k].z * inv; o0.w = acc0[k].w * inv;
        o1.x = acc1[k].x * inv; o1.y = acc1[k].y * inv;
        o1.z = acc1[k].z * inv; o1.w = acc1[k].w * inv;
        const int oidx = (bbase + (bi0 + ti + k) * NY + (bj0 + tj)) * 2;
        ov[oidx + 0] = o0;
        ov[oidx + 1] = o1;
    }
}

extern "C" void kernel_launch(void* const* d_in, const int* in_sizes, int n_in,
                              void* d_out, int out_size, void* d_ws, size_t ws_size,
                              hipStream_t stream) {
    const float4* x = (const float4*)d_in[0];
    float4* out = (float4*)d_out;
    dim3 grid(NY / TSJ, NX / TSI, BATCH);  // 8 x 16 x 8 = 1024 blocks
    nlm_kernel<<<grid, NTHREADS, 0, stream>>>(x, out);
}

// Round 5
// 74.862 us; speedup vs baseline: 1.2366x; 1.2366x over previous
//
#include <hip/hip_runtime.h>

// NLM smoothing: x[B=8, H=256, W=256, C=8] fp32, K=5, sigma=1, h=1, reflect pad.
//
// v6: RPT=2 vertical blocking, 256 threads (TSJ=32 x TSI=16), and crucially
// __launch_bounds__(256) with NO min-waves clause.
// Post-mortem v4/v5: both used a min-waves=4 clause -> 128-VGPR allocator cap
// on the fully-unrolled RPT=2 body (50 exp sites, hoisted LDS loads) ->
// scratch spills -> identical 92.6us for two different launch geometries.
// v3 (bigger body, 256-VGPR cap) showed no such cliff. Removing the cap lets
// the allocator land at its natural ~100 VGPR (~5 waves/SIMD).
// Kept: RPT=2 LDS-traffic win (6 rows x 5 cols = 30 px reads serve 2 outputs,
//       894 LDS cyc/wave vs RPT=1's 2x745);
//       SoA float4 LDS planes (16B lane stride, conflict-free);
//       w ∝ 2^(log2e*(2c·p - |p|^2 - 0.5(dr^2+dc^2))), exp(-|c|^2) cancels in
//       the w/sum(w) normalization; |p|^2*log2e staged per pixel; raw exp2.

#define BATCH 8
#define NX 256
#define NY 256
#define HALO 2
#define TSJ 32
#define TSI 16
#define RPT 2                 // output rows per thread
#define NTHREADS 256
#define LW (TSJ + 2 * HALO)   // 36
#define LH (TSI + 2 * HALO)   // 20
#define NPIX (LW * LH)        // 720

#define LOG2E 1.4426950408889634f

__device__ __forceinline__ int reflect_idx(int v) {
    // valid for v in [-2, 257] with N=256
    if (v < 0) v = -v;
    if (v > NY - 1) v = 2 * (NY - 1) - v;
    return v;
}

__global__ __launch_bounds__(NTHREADS) void nlm_kernel(const float4* __restrict__ xv,
                                                       float4* __restrict__ ov) {
    __shared__ float4 t0[NPIX];   // channels 0-3
    __shared__ float4 t1[NPIX];   // channels 4-7
    __shared__ float  tn[NPIX];   // |p|^2 * log2(e) per pixel

    const int t = threadIdx.x;
    const int bj0 = blockIdx.x * TSJ;
    const int bi0 = blockIdx.y * TSI;
    const int b = blockIdx.z;
    const int bbase = b * (NX * NY);

    // ---- stage 36x20 tile (with reflect halo) into LDS, SoA planes + norms ----
#pragma unroll
    for (int s0 = 0; s0 < NPIX; s0 += NTHREADS) {
        const int p = s0 + t;
        if (p < NPIX) {
            const int lr = p / LW;
            const int lc = p - lr * LW;
            const int gi = reflect_idx(bi0 + lr - HALO);
            const int gj = reflect_idx(bj0 + lc - HALO);
            const int gidx = (bbase + gi * NY + gj) * 2;
            const float4 v0 = xv[gidx + 0];
            const float4 v1 = xv[gidx + 1];
            t0[p] = v0;
            t1[p] = v1;
            tn[p] = (v0.x * v0.x + v0.y * v0.y + v0.z * v0.z + v0.w * v0.w +
                     v1.x * v1.x + v1.y * v1.y + v1.z * v1.z + v1.w * v1.w) * LOG2E;
        }
    }
    __syncthreads();

    // ---- per-thread: RPT=2 vertically adjacent pixels ----
    const int tj = t & (TSJ - 1);        // 0..31, contiguous within wave half
    const int ti = (t >> 5) * RPT;       // 0,2,...,14

    float4 cs0[RPT], cs1[RPT];           // centers pre-scaled by 2*log2(e)
#pragma unroll
    for (int k = 0; k < RPT; ++k) {
        const int cpix = (ti + HALO + k) * LW + (tj + HALO);
        const float4 c0 = t0[cpix];
        const float4 c1 = t1[cpix];
        const float s = 2.f * LOG2E;
        cs0[k] = make_float4(s * c0.x, s * c0.y, s * c0.z, s * c0.w);
        cs1[k] = make_float4(s * c1.x, s * c1.y, s * c1.z, s * c1.w);
    }

    float4 acc0[RPT], acc1[RPT];
    float wsum[RPT];
#pragma unroll
    for (int k = 0; k < RPT; ++k) {
        acc0[k] = make_float4(0.f, 0.f, 0.f, 0.f);
        acc1[k] = make_float4(0.f, 0.f, 0.f, 0.f);
        wsum[k] = 0.f;
    }

#pragma unroll
    for (int r = 0; r < RPT + 2 * HALO; ++r) {        // 6 neighbor rows
#pragma unroll
        for (int dc = -HALO; dc <= HALO; ++dc) {      // 5 neighbor cols
            const int pix = (ti + r) * LW + (tj + HALO + dc);
            const float4 p0 = t0[pix];
            const float4 p1 = t1[pix];
            const float pn = tn[pix];
#pragma unroll
            for (int k = 0; k < RPT; ++k) {           // feed valid centers
                const int dr = r - HALO - k;
                if (dr >= -HALO && dr <= HALO) {      // compile-time
                    // a = log2e * (2c.p - |p|^2 - 0.5*(dr^2+dc^2)); w = 2^a
                    float a = (-0.5f * LOG2E * (float)(dr * dr + dc * dc)) - pn;
                    a = fmaf(cs0[k].x, p0.x, a);
                    a = fmaf(cs0[k].y, p0.y, a);
                    a = fmaf(cs0[k].z, p0.z, a);
                    a = fmaf(cs0[k].w, p0.w, a);
                    a = fmaf(cs1[k].x, p1.x, a);
                    a = fmaf(cs1[k].y, p1.y, a);
                    a = fmaf(cs1[k].z, p1.z, a);
                    a = fmaf(cs1[k].w, p1.w, a);

                    const float w = __builtin_amdgcn_exp2f(a);

                    acc0[k].x = fmaf(w, p0.x, acc0[k].x);
                    acc0[k].y = fmaf(w, p0.y, acc0[k].y);
                    acc0[k].z = fmaf(w, p0.z, acc0[k].z);
                    acc0[k].w = fmaf(w, p0.w, acc0[k].w);
                    acc1[k].x = fmaf(w, p1.x, acc1[k].x);
                    acc1[k].y = fmaf(w, p1.y, acc1[k].y);
                    acc1[k].z = fmaf(w, p1.z, acc1[k].z);
                    acc1[k].w = fmaf(w, p1.w, acc1[k].w);
                    wsum[k] += w;
                }
            }
        }
    }

#pragma unroll
    for (int k = 0; k < RPT; ++k) {
        const float inv = 1.0f / wsum[k];
        float4 o0, o1;
        o0.x = acc0[k].x * inv; o0.y = acc0[k].y * inv;
        o0.z = acc0[k].z * inv; o0.w = acc0[k].w * inv;
        o1.x = acc1[k].x * inv; o1.y = acc1[k].y * inv;
        o1.z = acc1[k].z * inv; o1.w = acc1[k].w * inv;
        const int oidx = (bbase + (bi0 + ti + k) * NY + (bj0 + tj)) * 2;
        ov[oidx + 0] = o0;
        ov[oidx + 1] = o1;
    }
}

extern "C" void kernel_launch(void* const* d_in, const int* in_sizes, int n_in,
                              void* d_out, int out_size, void* d_ws, size_t ws_size,
                              hipStream_t stream) {
    const float4* x = (const float4*)d_in[0];
    float4* out = (float4*)d_out;
    dim3 grid(NY / TSJ, NX / TSI, BATCH);  // 8 x 16 x 8 = 1024 blocks
    nlm_kernel<<<grid, NTHREADS, 0, stream>>>(x, out);
}